// Round 12
// baseline (151.962 us; speedup 1.0000x reference)
//
#include <hip/hip_runtime.h>

// TimeSeriesAttention B=4,T=4096,D=64 fp32 — all-MFMA pipeline, depth-1
// software pipeline in pass B, PV hi-only, atomic epilogue (no slabs/reduce).
//  enc = tanh(softmax(x@W1+b1)@W2+b2)
//  s[j,i]=<x_j,enc_i>; P[j,:] = exp(s)/Z_j ; out[i,d] = sum_j P[j,i] x[j,d]
// Packed layouts (verified rounds 2-11):
//  A/B-frag arrays: [slice(16 rows)][kc(2)][quad(4)][m16][t8] f16
//    (flat: slice*1024 + kc*512 + quad*128 + l15*8)
//  PV-B array xtf:  [b][slice][quad][d64][8] with [0:4]=hi,[4:8]=lo
// 16x16x32: A[m=l15][k=quad*8+t], B[n=l15][k=quad*8+t], D[col=l15][row=quad*4+r]
// 16x16x16: A/B[idx=l15][k=quad*4+t], same D. C-layout == 16x16x16 A/B-frag
// with k=quad*4+r (the P identity) — chains QK^T->PV and MLP layer1->layer2.

typedef _Float16 f16;
typedef __attribute__((ext_vector_type(8))) _Float16 f16x8;
typedef __attribute__((ext_vector_type(4))) _Float16 f16x4;
typedef __attribute__((ext_vector_type(4))) float f32x4;

#define TT 4096
#define BB 4
#define BT (BB*TT)
#define SPLIT_A 16
#define NSPLIT_B 8

#define MFMA32(A,B,C) __builtin_amdgcn_mfma_f32_16x16x32_f16(A,B,C,0,0,0)
#define MFMA16(A,B,C) __builtin_amdgcn_mfma_f32_16x16x16f16(A,B,C,0,0,0)

#if __has_builtin(__builtin_amdgcn_exp2f)
#define EXP2F(x) __builtin_amdgcn_exp2f(x)
#else
#define EXP2F(x) exp2f(x)
#endif

#define LOG2E 1.4426950408889634f

// ---- wpack: W1 -> A-frag(16x16x32) hi/lo, W2 -> A-frag(16x16x16) hi/lo ---
__global__ __launch_bounds__(256) void k_wpack(
    const float* __restrict__ W1, const float* __restrict__ W2,
    f16* __restrict__ w1fh, f16* __restrict__ w1fl,
    f16* __restrict__ w2fh, f16* __restrict__ w2fl) {
  int tid = threadIdx.x;
#pragma unroll
  for (int k2 = 0; k2 < 2; ++k2) {
    int idx = tid * 2 + k2;
    int l15 = idx & 15, quad = (idx >> 4) & 3, kc = (idx >> 6) & 1, mtW = idx >> 7;
    f16 h8[8], l8[8];
#pragma unroll
    for (int t = 0; t < 8; ++t) {
      float v = W1[(size_t)(kc * 32 + quad * 8 + t) * 64 + mtW * 16 + l15];
      f16 h = (f16)v;
      h8[t] = h; l8[t] = (f16)(v - (float)h);
    }
    *(f16x8*)(w1fh + (size_t)idx * 8) = *(f16x8*)h8;
    *(f16x8*)(w1fl + (size_t)idx * 8) = *(f16x8*)l8;
  }
#pragma unroll
  for (int k4 = 0; k4 < 4; ++k4) {
    int idx = tid * 4 + k4;
    int l15 = idx & 15, quad = (idx >> 4) & 3, kt = (idx >> 6) & 3, mt2 = idx >> 8;
    f16 h4[4], l4[4];
#pragma unroll
    for (int t = 0; t < 4; ++t) {
      float v = W2[(size_t)(kt * 16 + quad * 4 + t) * 64 + mt2 * 16 + l15];
      f16 h = (f16)v;
      h4[t] = h; l4[t] = (f16)(v - (float)h);
    }
    *(f16x4*)(w2fh + (size_t)idx * 4) = *(f16x4*)h4;
    *(f16x4*)(w2fl + (size_t)idx * 4) = *(f16x4*)l4;
  }
}

// ---- encode: MFMA MLP, one 16-row slice per wave, no barriers -----------
// Also zero-inits Zbuf and this block's 16 KB chunk of out (atomic epilogue
// target) — replaces two memset launches.
__global__ __launch_bounds__(256, 1) void k_encode(
    const float* __restrict__ x,
    const float* __restrict__ b1, const float* __restrict__ b2,
    const f16* __restrict__ w1fh, const f16* __restrict__ w1fl,
    const f16* __restrict__ w2fh, const f16* __restrict__ w2fl,
    f16* __restrict__ ench, f16* __restrict__ encl,
    f16* __restrict__ xafh, f16* __restrict__ xafl, f16* __restrict__ xtf,
    float* __restrict__ Zbuf, float* __restrict__ out) {
  __shared__ float xS[4][16][68];
  __shared__ float encS[4][16][68];
  int tid = threadIdx.x;
  int w = tid >> 6, lane = tid & 63, quad = lane >> 4, l15 = lane & 15;
  if (tid < 64) Zbuf[blockIdx.x * 64 + tid] = 0.f;
  {
    float4 z4 = make_float4(0.f, 0.f, 0.f, 0.f);
#pragma unroll
    for (int k = 0; k < 4; ++k)
      ((float4*)out)[(size_t)blockIdx.x * 1024 + k * 256 + tid] = z4;
  }
  int slice = blockIdx.x * 4 + w;
  int base = slice * 16;
  // --- load W fragments (hi+lo) ---
  f16x8 w1h[4][2], w1l[4][2];
#pragma unroll
  for (int mt = 0; mt < 4; ++mt)
#pragma unroll
    for (int kc = 0; kc < 2; ++kc) {
      size_t off = (size_t)(((mt * 2 + kc) * 4 + quad) * 16 + l15) * 8;
      w1h[mt][kc] = *(const f16x8*)(w1fh + off);
      w1l[mt][kc] = *(const f16x8*)(w1fl + off);
    }
  f16x4 w2h[4][4], w2l[4][4];
#pragma unroll
  for (int mt = 0; mt < 4; ++mt)
#pragma unroll
    for (int kt = 0; kt < 4; ++kt) {
      size_t off = (size_t)(((mt * 4 + kt) * 4 + quad) * 16 + l15) * 4;
      w2h[mt][kt] = *(const f16x4*)(w2fh + off);
      w2l[mt][kt] = *(const f16x4*)(w2fl + off);
    }
  // --- load x as B-frag (== xaf layout), store xaf, stage xS ---
  f16x8 xbh[2], xbl[2];
#pragma unroll
  for (int kc = 0; kc < 2; ++kc) {
    const float4* p = (const float4*)(x + (size_t)(base + l15) * 64 + kc * 32 + quad * 8);
    float4 v0 = p[0], v1 = p[1];
    float v[8] = {v0.x, v0.y, v0.z, v0.w, v1.x, v1.y, v1.z, v1.w};
    f16 h8[8], l8[8];
#pragma unroll
    for (int t = 0; t < 8; ++t) {
      f16 h = (f16)v[t];
      h8[t] = h; l8[t] = (f16)(v[t] - (float)h);
    }
    xbh[kc] = *(f16x8*)h8;
    xbl[kc] = *(f16x8*)l8;
    size_t off = (size_t)slice * 1024 + kc * 512 + quad * 128 + l15 * 8;
    *(f16x8*)(xafh + off) = xbh[kc];
    *(f16x8*)(xafl + off) = xbl[kc];
    *(float4*)&xS[w][l15][kc * 32 + quad * 8] = v0;
    *(float4*)&xS[w][l15][kc * 32 + quad * 8 + 4] = v1;
  }
  // --- layer 1 (3-product) ---
  f32x4 acc1[4];
#pragma unroll
  for (int mt = 0; mt < 4; ++mt) {
    f32x4 z = {0.f, 0.f, 0.f, 0.f};
    acc1[mt] = z;
  }
#pragma unroll
  for (int kc = 0; kc < 2; ++kc)
#pragma unroll
    for (int mt = 0; mt < 4; ++mt) {
      acc1[mt] = MFMA32(w1h[mt][kc], xbh[kc], acc1[mt]);
      acc1[mt] = MFMA32(w1h[mt][kc], xbl[kc], acc1[mt]);
      acc1[mt] = MFMA32(w1l[mt][kc], xbh[kc], acc1[mt]);
    }
  float h1[4][4];
#pragma unroll
  for (int mt = 0; mt < 4; ++mt) {
    float4 bv = *(const float4*)(b1 + mt * 16 + quad * 4);
    h1[mt][0] = acc1[mt][0] + bv.x;
    h1[mt][1] = acc1[mt][1] + bv.y;
    h1[mt][2] = acc1[mt][2] + bv.z;
    h1[mt][3] = acc1[mt][3] + bv.w;
  }
  // --- softmax over e1 ---
  float m1 = h1[0][0];
#pragma unroll
  for (int mt = 0; mt < 4; ++mt)
#pragma unroll
    for (int r = 0; r < 4; ++r) m1 = fmaxf(m1, h1[mt][r]);
  m1 = fmaxf(m1, __shfl_xor(m1, 16));
  m1 = fmaxf(m1, __shfl_xor(m1, 32));
  float ssum = 0.f;
  float ev[4][4];
#pragma unroll
  for (int mt = 0; mt < 4; ++mt)
#pragma unroll
    for (int r = 0; r < 4; ++r) {
      ev[mt][r] = EXP2F((h1[mt][r] - m1) * LOG2E);
      ssum += ev[mt][r];
    }
  ssum += __shfl_xor(ssum, 16);
  ssum += __shfl_xor(ssum, 32);
  float rs = __builtin_amdgcn_rcpf(ssum);
  f16x4 p1h[4], p1l[4];
#pragma unroll
  for (int mt = 0; mt < 4; ++mt)
#pragma unroll
    for (int r = 0; r < 4; ++r) {
      float p = ev[mt][r] * rs;
      f16 h = (f16)p;
      p1h[mt][r] = h;
      p1l[mt][r] = (f16)(p - (float)h);
    }
  // --- layer 2 (3-product) ---
  f32x4 acc2[4];
#pragma unroll
  for (int mt = 0; mt < 4; ++mt) {
    f32x4 z = {0.f, 0.f, 0.f, 0.f};
    acc2[mt] = z;
  }
#pragma unroll
  for (int kt = 0; kt < 4; ++kt)
#pragma unroll
    for (int mt = 0; mt < 4; ++mt) {
      acc2[mt] = MFMA16(w2h[mt][kt], p1h[kt], acc2[mt]);
      acc2[mt] = MFMA16(w2h[mt][kt], p1l[kt], acc2[mt]);
      acc2[mt] = MFMA16(w2l[mt][kt], p1h[kt], acc2[mt]);
    }
  // enc = tanh(acc2 + b2) * LOG2E
#pragma unroll
  for (int mt = 0; mt < 4; ++mt) {
    float4 bv = *(const float4*)(b2 + mt * 16 + quad * 4);
    float bb[4] = {bv.x, bv.y, bv.z, bv.w};
    float o4[4];
#pragma unroll
    for (int r = 0; r < 4; ++r) {
      float hv = acc2[mt][r] + bb[r];
      float ex = EXP2F(hv * (2.0f * LOG2E));
      float th = 1.0f - 2.0f * __builtin_amdgcn_rcpf(ex + 1.0f);
      o4[r] = th * LOG2E;
    }
    *(float4*)&encS[w][l15][mt * 16 + quad * 4] = *(float4*)o4;
  }
  // --- pack ench/encl from encS (wave-private) ---
#pragma unroll
  for (int k = 0; k < 2; ++k) {
    int e = k * 64 + lane;
    int n = e & 15, quad2 = (e >> 4) & 3, kc = e >> 6;
    const float4* p = (const float4*)&encS[w][n][kc * 32 + quad2 * 8];
    float4 v0 = p[0], v1 = p[1];
    float v[8] = {v0.x, v0.y, v0.z, v0.w, v1.x, v1.y, v1.z, v1.w};
    f16 h8[8], l8[8];
#pragma unroll
    for (int t = 0; t < 8; ++t) {
      f16 h = (f16)v[t];
      h8[t] = h; l8[t] = (f16)(v[t] - (float)h);
    }
    *(f16x8*)(ench + ((size_t)slice * 128 + e) * 8) = *(f16x8*)h8;
    *(f16x8*)(encl + ((size_t)slice * 128 + e) * 8) = *(f16x8*)l8;
  }
  // --- pack xtf from xS ---
  int b = slice >> 8, ls = slice & 255;
#pragma unroll
  for (int k = 0; k < 4; ++k) {
    f16 p8[8];
#pragma unroll
    for (int t = 0; t < 4; ++t) {
      float v = xS[w][k * 4 + t][lane];
      f16 h = (f16)v;
      p8[t] = h; p8[4 + t] = (f16)(v - (float)h);
    }
    size_t off = ((((size_t)b * (TT / 16) + ls) * 4 + k) * 64 + lane) * 8;
    *(f16x8*)(xtf + off) = *(f16x8*)p8;
  }
}

// ---- pass A: Z[j] = sum_i exp2(s'[j,i]); single-product f16 scores ------
__global__ __launch_bounds__(512, 4) void k_statsM(
    const f16* __restrict__ xafh, const f16* __restrict__ ench,
    float* __restrict__ Zbuf) {
  int tid = threadIdx.x;
  int w = tid >> 6, lane = tid & 63, quad = lane >> 4, l15 = lane & 15;
  int jb = blockIdx.x * 256 + w * 32;
  int b = jb >> 12;
  f16x8 xa[2][2];
#pragma unroll
  for (int mt = 0; mt < 2; ++mt)
#pragma unroll
    for (int kc = 0; kc < 2; ++kc) {
      size_t off = (size_t)((jb >> 4) + mt) * 1024 + kc * 512 + quad * 128 + l15 * 8;
      xa[mt][kc] = *(const f16x8*)(xafh + off);
    }
  float l_run[8];
#pragma unroll
  for (int s = 0; s < 8; ++s) l_run[s] = 0.f;
  int i0 = blockIdx.y * (TT / SPLIT_A);
  size_t ebase = (size_t)((b * TT + i0) >> 4) * 1024 + quad * 128 + l15 * 8;
  const f16* pEh = ench + ebase;
  for (int it = 0; it < TT / SPLIT_A / 64; ++it) {
    f32x4 acc[2][4];
#pragma unroll
    for (int mt = 0; mt < 2; ++mt)
#pragma unroll
      for (int nt = 0; nt < 4; ++nt) {
        f32x4 z = {0.f, 0.f, 0.f, 0.f};
        acc[mt][nt] = z;
      }
#pragma unroll
    for (int kc = 0; kc < 2; ++kc) {
      f16x8 ebf[4];
#pragma unroll
      for (int nt = 0; nt < 4; ++nt)
        ebf[nt] = *(const f16x8*)(pEh + nt * 1024 + kc * 512);
#pragma unroll
      for (int mt = 0; mt < 2; ++mt)
#pragma unroll
        for (int nt = 0; nt < 4; ++nt)
          acc[mt][nt] = MFMA32(xa[mt][kc], ebf[nt], acc[mt][nt]);
    }
#pragma unroll
    for (int mt = 0; mt < 2; ++mt)
#pragma unroll
      for (int r = 0; r < 4; ++r)
        l_run[mt * 4 + r] += EXP2F(acc[mt][0][r]) + EXP2F(acc[mt][1][r]) +
                             EXP2F(acc[mt][2][r]) + EXP2F(acc[mt][3][r]);
    pEh += 4096;
  }
#pragma unroll
  for (int s = 0; s < 8; ++s) {
    float l = l_run[s];
#pragma unroll
    for (int off = 1; off < 16; off <<= 1) l += __shfl_xor(l, off);
    l_run[s] = l;
  }
  if (l15 == 0) {
#pragma unroll
    for (int mt = 0; mt < 2; ++mt)
#pragma unroll
      for (int r = 0; r < 4; ++r)
        atomicAdd(Zbuf + jb + mt * 16 + quad * 4 + r, l_run[mt * 4 + r]);
  }
}

// ---- pass B: 8 waves share j-stream; depth-1 pipeline; atomic epilogue --
__global__ __launch_bounds__(512, 4) void k_outB(
    const f16* __restrict__ xafh, const f16* __restrict__ xafl,
    const f16* __restrict__ xtf,
    const f16* __restrict__ ench, const f16* __restrict__ encl,
    const float* __restrict__ Zv, float* __restrict__ out, int jlen) {
  int tid = threadIdx.x;
  int w = tid >> 6, lane = tid & 63, quad = lane >> 4, l15 = lane & 15;
  int ibase = blockIdx.x * 256;
  int iw = ibase + w * 32;
  int b = ibase >> 12;
  f16x8 ebr[2][2][2];
#pragma unroll
  for (int nt = 0; nt < 2; ++nt)
#pragma unroll
    for (int kc = 0; kc < 2; ++kc) {
      size_t off = (size_t)((iw >> 4) + nt) * 1024 + kc * 512 + quad * 128 + l15 * 8;
      ebr[nt][kc][0] = *(const f16x8*)(ench + off);
      ebr[nt][kc][1] = *(const f16x8*)(encl + off);
    }
  f32x4 oacc[2][4];
#pragma unroll
  for (int nt = 0; nt < 2; ++nt)
#pragma unroll
    for (int mtb = 0; mtb < 4; ++mtb) {
      f32x4 z = {0.f, 0.f, 0.f, 0.f};
      oacc[nt][mtb] = z;
    }
  int jt0 = blockIdx.y * jlen;
  int nit = jlen / 16;
  size_t jf0 = (size_t)b * TT + jt0;
  const f16* pAh = xafh + (jf0 >> 4) * 1024 + quad * 128 + l15 * 8;
  const f16* pAl = xafl + (jf0 >> 4) * 1024 + quad * 128 + l15 * 8;
  const f16* pPV = xtf + ((size_t)b * (TT / 16) + (jt0 >> 4)) * 2048 +
                   quad * 512 + l15 * 8;
  const float* pZ = Zv + jf0 + quad * 4;
  // preload tile 0 (all streams)
  f16x8 cah[2], cal[2];
  f16x4 cpv[4];
  float4 cZ;
  cah[0] = *(const f16x8*)(pAh);       cah[1] = *(const f16x8*)(pAh + 512);
  cal[0] = *(const f16x8*)(pAl);       cal[1] = *(const f16x8*)(pAl + 512);
#pragma unroll
  for (int mtb = 0; mtb < 4; ++mtb)
    cpv[mtb] = *(const f16x4*)(pPV + mtb * 128);   // hi half only
  cZ = *(const float4*)pZ;
  pAh += 1024; pAl += 1024; pPV += 2048; pZ += 16;
  for (int t = 0; t < nit; ++t) {
    // prefetch tile t+1 (over-reads stay inside d_ws on last iter)
    f16x8 nah[2], nal[2];
    f16x4 npv[4];
    float4 nZ;
    nah[0] = *(const f16x8*)(pAh);     nah[1] = *(const f16x8*)(pAh + 512);
    nal[0] = *(const f16x8*)(pAl);     nal[1] = *(const f16x8*)(pAl + 512);
#pragma unroll
    for (int mtb = 0; mtb < 4; ++mtb)
      npv[mtb] = *(const f16x4*)(pPV + mtb * 128);
    nZ = *(const float4*)pZ;
    // sT: rows j (16), cols i (wave's 32), 3-product
    f32x4 sacc[2];
#pragma unroll
    for (int nt = 0; nt < 2; ++nt) {
      f32x4 z = {0.f, 0.f, 0.f, 0.f};
      sacc[nt] = z;
    }
#pragma unroll
    for (int kc = 0; kc < 2; ++kc)
#pragma unroll
      for (int nt = 0; nt < 2; ++nt) {
        sacc[nt] = MFMA32(cah[kc], ebr[nt][kc][0], sacc[nt]);
        sacc[nt] = MFMA32(cah[kc], ebr[nt][kc][1], sacc[nt]);
        sacc[nt] = MFMA32(cal[kc], ebr[nt][kc][0], sacc[nt]);
      }
    // P = exp2(s') * rZ (PV A-frag layout), hi only
    float rz[4] = {__builtin_amdgcn_rcpf(cZ.x), __builtin_amdgcn_rcpf(cZ.y),
                   __builtin_amdgcn_rcpf(cZ.z), __builtin_amdgcn_rcpf(cZ.w)};
    f16x4 pbh[2];
#pragma unroll
    for (int nt = 0; nt < 2; ++nt)
#pragma unroll
      for (int r = 0; r < 4; ++r)
        pbh[nt][r] = (f16)(EXP2F(sacc[nt][r]) * rz[r]);
    // PV: oacc[i,d] += P^T x_hi over this 16-j slice
#pragma unroll
    for (int mtb = 0; mtb < 4; ++mtb)
#pragma unroll
      for (int nt = 0; nt < 2; ++nt)
        oacc[nt][mtb] = MFMA16(pbh[nt], cpv[mtb], oacc[nt][mtb]);
    // rotate
    cah[0] = nah[0]; cah[1] = nah[1];
    cal[0] = nal[0]; cal[1] = nal[1];
#pragma unroll
    for (int mtb = 0; mtb < 4; ++mtb) cpv[mtb] = npv[mtb];
    cZ = nZ;
    pAh += 1024; pAl += 1024; pPV += 2048; pZ += 16;
  }
  // atomic epilogue: D[m=i (quad*4+r), n=d (l15)]; out is L2-resident (4 MB)
#pragma unroll
  for (int nt = 0; nt < 2; ++nt)
#pragma unroll
    for (int r = 0; r < 4; ++r) {
      int i = iw + nt * 16 + quad * 4 + r;
#pragma unroll
      for (int mtb = 0; mtb < 4; ++mtb)
        atomicAdd(out + (size_t)i * 64 + mtb * 16 + l15, oacc[nt][mtb][r]);
    }
}

extern "C" void kernel_launch(void* const* d_in, const int* in_sizes, int n_in,
                              void* d_out, int out_size, void* d_ws,
                              size_t ws_size, hipStream_t stream) {
  const float* x = (const float*)d_in[0];
  const float* W1 = (const float*)d_in[1];
  const float* b1 = (const float*)d_in[2];
  const float* W2 = (const float*)d_in[3];
  const float* b2 = (const float*)d_in[4];
  float* out = (float*)d_out;

  f16* xafh = (f16*)d_ws;                       // 2 MB
  f16* xafl = xafh + (size_t)BT * 64;           // 2 MB
  f16* xtf  = xafl + (size_t)BT * 64;           // 4 MB
  f16* ench = xtf + (size_t)BT * 128;           // 2 MB
  f16* encl = ench + (size_t)BT * 64;           // 2 MB
  float* Zv = (float*)(encl + (size_t)BT * 64); // 64 KB
  f16* w1fh = (f16*)(Zv + BT + 1024);           // +pad for Z over-read
  f16* w1fl = w1fh + 4096;                      // 8 KB each
  f16* w2fh = w1fl + 4096;
  f16* w2fl = w2fh + 4096;

  k_wpack<<<dim3(1), dim3(256), 0, stream>>>(W1, W2, w1fh, w1fl, w2fh, w2fl);
  k_encode<<<dim3(BT / 64), dim3(256), 0, stream>>>(
      x, b1, b2, w1fh, w1fl, w2fh, w2fl, ench, encl, xafh, xafl, xtf, Zv, out);
  k_statsM<<<dim3(BT / 256, SPLIT_A), dim3(512), 0, stream>>>(xafh, ench, Zv);
  k_outB<<<dim3(BT / 256, NSPLIT_B), dim3(512), 0, stream>>>(
      xafh, xafl, xtf, ench, encl, Zv, out, TT / NSPLIT_B);
}

// Round 13
// 143.329 us; speedup vs baseline: 1.0602x; 1.0602x over previous
//
#include <hip/hip_runtime.h>

// TimeSeriesAttention B=4,T=4096,D=64 fp32 — all-MFMA pipeline, depth-1
// software pipeline + kc-split score chains in pass B, PV hi-only,
// slab-store epilogue (atomics measured 17us slower in R12).
//  enc = tanh(softmax(x@W1+b1)@W2+b2)
//  s[j,i]=<x_j,enc_i>; P[j,:] = exp(s)/Z_j ; out[i,d] = sum_j P[j,i] x[j,d]
// Packed layouts (verified rounds 2-12):
//  A/B-frag arrays: [slice(16 rows)][kc(2)][quad(4)][m16][t8] f16
//    (flat: slice*1024 + kc*512 + quad*128 + l15*8)
//  PV-B array xtf:  [b][slice][quad][d64][8] with [0:4]=hi,[4:8]=lo
// 16x16x32: A[m=l15][k=quad*8+t], B[n=l15][k=quad*8+t], D[col=l15][row=quad*4+r]
// 16x16x16: A/B[idx=l15][k=quad*4+t], same D. C-layout == 16x16x16 A/B-frag
// with k=quad*4+r (the P identity) — chains QK^T->PV and MLP layer1->layer2.

typedef _Float16 f16;
typedef __attribute__((ext_vector_type(8))) _Float16 f16x8;
typedef __attribute__((ext_vector_type(4))) _Float16 f16x4;
typedef __attribute__((ext_vector_type(4))) float f32x4;

#define TT 4096
#define BB 4
#define BT (BB*TT)
#define SPLIT_A 16
#define NSPLIT_B 8

#define MFMA32(A,B,C) __builtin_amdgcn_mfma_f32_16x16x32_f16(A,B,C,0,0,0)
#define MFMA16(A,B,C) __builtin_amdgcn_mfma_f32_16x16x16f16(A,B,C,0,0,0)

#if __has_builtin(__builtin_amdgcn_exp2f)
#define EXP2F(x) __builtin_amdgcn_exp2f(x)
#else
#define EXP2F(x) exp2f(x)
#endif

#define LOG2E 1.4426950408889634f

// ---- wpack: W1 -> A-frag(16x16x32) hi/lo, W2 -> A-frag(16x16x16) hi/lo ---
__global__ __launch_bounds__(256) void k_wpack(
    const float* __restrict__ W1, const float* __restrict__ W2,
    f16* __restrict__ w1fh, f16* __restrict__ w1fl,
    f16* __restrict__ w2fh, f16* __restrict__ w2fl) {
  int tid = threadIdx.x;
#pragma unroll
  for (int k2 = 0; k2 < 2; ++k2) {
    int idx = tid * 2 + k2;
    int l15 = idx & 15, quad = (idx >> 4) & 3, kc = (idx >> 6) & 1, mtW = idx >> 7;
    f16 h8[8], l8[8];
#pragma unroll
    for (int t = 0; t < 8; ++t) {
      float v = W1[(size_t)(kc * 32 + quad * 8 + t) * 64 + mtW * 16 + l15];
      f16 h = (f16)v;
      h8[t] = h; l8[t] = (f16)(v - (float)h);
    }
    *(f16x8*)(w1fh + (size_t)idx * 8) = *(f16x8*)h8;
    *(f16x8*)(w1fl + (size_t)idx * 8) = *(f16x8*)l8;
  }
#pragma unroll
  for (int k4 = 0; k4 < 4; ++k4) {
    int idx = tid * 4 + k4;
    int l15 = idx & 15, quad = (idx >> 4) & 3, kt = (idx >> 6) & 3, mt2 = idx >> 8;
    f16 h4[4], l4[4];
#pragma unroll
    for (int t = 0; t < 4; ++t) {
      float v = W2[(size_t)(kt * 16 + quad * 4 + t) * 64 + mt2 * 16 + l15];
      f16 h = (f16)v;
      h4[t] = h; l4[t] = (f16)(v - (float)h);
    }
    *(f16x4*)(w2fh + (size_t)idx * 4) = *(f16x4*)h4;
    *(f16x4*)(w2fl + (size_t)idx * 4) = *(f16x4*)l4;
  }
}

// ---- encode: MFMA MLP, one 16-row slice per wave, no barriers -----------
__global__ __launch_bounds__(256, 1) void k_encode(
    const float* __restrict__ x,
    const float* __restrict__ b1, const float* __restrict__ b2,
    const f16* __restrict__ w1fh, const f16* __restrict__ w1fl,
    const f16* __restrict__ w2fh, const f16* __restrict__ w2fl,
    f16* __restrict__ ench, f16* __restrict__ encl,
    f16* __restrict__ xafh, f16* __restrict__ xafl, f16* __restrict__ xtf,
    float* __restrict__ Zbuf) {
  __shared__ float xS[4][16][68];
  __shared__ float encS[4][16][68];
  int tid = threadIdx.x;
  int w = tid >> 6, lane = tid & 63, quad = lane >> 4, l15 = lane & 15;
  if (tid < 64) Zbuf[blockIdx.x * 64 + tid] = 0.f;
  int slice = blockIdx.x * 4 + w;
  int base = slice * 16;
  // --- load W fragments (hi+lo) from packed ws ---
  f16x8 w1h[4][2], w1l[4][2];
#pragma unroll
  for (int mt = 0; mt < 4; ++mt)
#pragma unroll
    for (int kc = 0; kc < 2; ++kc) {
      size_t off = (size_t)(((mt * 2 + kc) * 4 + quad) * 16 + l15) * 8;
      w1h[mt][kc] = *(const f16x8*)(w1fh + off);
      w1l[mt][kc] = *(const f16x8*)(w1fl + off);
    }
  f16x4 w2h[4][4], w2l[4][4];
#pragma unroll
  for (int mt = 0; mt < 4; ++mt)
#pragma unroll
    for (int kt = 0; kt < 4; ++kt) {
      size_t off = (size_t)(((mt * 4 + kt) * 4 + quad) * 16 + l15) * 4;
      w2h[mt][kt] = *(const f16x4*)(w2fh + off);
      w2l[mt][kt] = *(const f16x4*)(w2fl + off);
    }
  // --- load x as B-frag (== xaf layout), store xaf, stage xS ---
  f16x8 xbh[2], xbl[2];
#pragma unroll
  for (int kc = 0; kc < 2; ++kc) {
    const float4* p = (const float4*)(x + (size_t)(base + l15) * 64 + kc * 32 + quad * 8);
    float4 v0 = p[0], v1 = p[1];
    float v[8] = {v0.x, v0.y, v0.z, v0.w, v1.x, v1.y, v1.z, v1.w};
    f16 h8[8], l8[8];
#pragma unroll
    for (int t = 0; t < 8; ++t) {
      f16 h = (f16)v[t];
      h8[t] = h; l8[t] = (f16)(v[t] - (float)h);
    }
    xbh[kc] = *(f16x8*)h8;
    xbl[kc] = *(f16x8*)l8;
    size_t off = (size_t)slice * 1024 + kc * 512 + quad * 128 + l15 * 8;
    *(f16x8*)(xafh + off) = xbh[kc];
    *(f16x8*)(xafl + off) = xbl[kc];
    *(float4*)&xS[w][l15][kc * 32 + quad * 8] = v0;
    *(float4*)&xS[w][l15][kc * 32 + quad * 8 + 4] = v1;
  }
  // --- layer 1 (3-product) ---
  f32x4 acc1[4];
#pragma unroll
  for (int mt = 0; mt < 4; ++mt) {
    f32x4 z = {0.f, 0.f, 0.f, 0.f};
    acc1[mt] = z;
  }
#pragma unroll
  for (int kc = 0; kc < 2; ++kc)
#pragma unroll
    for (int mt = 0; mt < 4; ++mt) {
      acc1[mt] = MFMA32(w1h[mt][kc], xbh[kc], acc1[mt]);
      acc1[mt] = MFMA32(w1h[mt][kc], xbl[kc], acc1[mt]);
      acc1[mt] = MFMA32(w1l[mt][kc], xbh[kc], acc1[mt]);
    }
  float h1[4][4];
#pragma unroll
  for (int mt = 0; mt < 4; ++mt) {
    float4 bv = *(const float4*)(b1 + mt * 16 + quad * 4);
    h1[mt][0] = acc1[mt][0] + bv.x;
    h1[mt][1] = acc1[mt][1] + bv.y;
    h1[mt][2] = acc1[mt][2] + bv.z;
    h1[mt][3] = acc1[mt][3] + bv.w;
  }
  // --- softmax over e1 ---
  float m1 = h1[0][0];
#pragma unroll
  for (int mt = 0; mt < 4; ++mt)
#pragma unroll
    for (int r = 0; r < 4; ++r) m1 = fmaxf(m1, h1[mt][r]);
  m1 = fmaxf(m1, __shfl_xor(m1, 16));
  m1 = fmaxf(m1, __shfl_xor(m1, 32));
  float ssum = 0.f;
  float ev[4][4];
#pragma unroll
  for (int mt = 0; mt < 4; ++mt)
#pragma unroll
    for (int r = 0; r < 4; ++r) {
      ev[mt][r] = EXP2F((h1[mt][r] - m1) * LOG2E);
      ssum += ev[mt][r];
    }
  ssum += __shfl_xor(ssum, 16);
  ssum += __shfl_xor(ssum, 32);
  float rs = __builtin_amdgcn_rcpf(ssum);
  f16x4 p1h[4], p1l[4];
#pragma unroll
  for (int mt = 0; mt < 4; ++mt)
#pragma unroll
    for (int r = 0; r < 4; ++r) {
      float p = ev[mt][r] * rs;
      f16 h = (f16)p;
      p1h[mt][r] = h;
      p1l[mt][r] = (f16)(p - (float)h);
    }
  // --- layer 2 (3-product) ---
  f32x4 acc2[4];
#pragma unroll
  for (int mt = 0; mt < 4; ++mt) {
    f32x4 z = {0.f, 0.f, 0.f, 0.f};
    acc2[mt] = z;
  }
#pragma unroll
  for (int kt = 0; kt < 4; ++kt)
#pragma unroll
    for (int mt = 0; mt < 4; ++mt) {
      acc2[mt] = MFMA16(w2h[mt][kt], p1h[kt], acc2[mt]);
      acc2[mt] = MFMA16(w2h[mt][kt], p1l[kt], acc2[mt]);
      acc2[mt] = MFMA16(w2l[mt][kt], p1h[kt], acc2[mt]);
    }
  // enc = tanh(acc2 + b2) * LOG2E
#pragma unroll
  for (int mt = 0; mt < 4; ++mt) {
    float4 bv = *(const float4*)(b2 + mt * 16 + quad * 4);
    float bb[4] = {bv.x, bv.y, bv.z, bv.w};
    float o4[4];
#pragma unroll
    for (int r = 0; r < 4; ++r) {
      float hv = acc2[mt][r] + bb[r];
      float ex = EXP2F(hv * (2.0f * LOG2E));
      float th = 1.0f - 2.0f * __builtin_amdgcn_rcpf(ex + 1.0f);
      o4[r] = th * LOG2E;
    }
    *(float4*)&encS[w][l15][mt * 16 + quad * 4] = *(float4*)o4;
  }
  // --- pack ench/encl from encS (wave-private) ---
#pragma unroll
  for (int k = 0; k < 2; ++k) {
    int e = k * 64 + lane;
    int n = e & 15, quad2 = (e >> 4) & 3, kc = e >> 6;
    const float4* p = (const float4*)&encS[w][n][kc * 32 + quad2 * 8];
    float4 v0 = p[0], v1 = p[1];
    float v[8] = {v0.x, v0.y, v0.z, v0.w, v1.x, v1.y, v1.z, v1.w};
    f16 h8[8], l8[8];
#pragma unroll
    for (int t = 0; t < 8; ++t) {
      f16 h = (f16)v[t];
      h8[t] = h; l8[t] = (f16)(v[t] - (float)h);
    }
    *(f16x8*)(ench + ((size_t)slice * 128 + e) * 8) = *(f16x8*)h8;
    *(f16x8*)(encl + ((size_t)slice * 128 + e) * 8) = *(f16x8*)l8;
  }
  // --- pack xtf from xS ---
  int b = slice >> 8, ls = slice & 255;
#pragma unroll
  for (int k = 0; k < 4; ++k) {
    f16 p8[8];
#pragma unroll
    for (int t = 0; t < 4; ++t) {
      float v = xS[w][k * 4 + t][lane];
      f16 h = (f16)v;
      p8[t] = h; p8[4 + t] = (f16)(v - (float)h);
    }
    size_t off = ((((size_t)b * (TT / 16) + ls) * 4 + k) * 64 + lane) * 8;
    *(f16x8*)(xtf + off) = *(f16x8*)p8;
  }
}

// ---- pass A: Z[j] = sum_i exp2(s'[j,i]); single-product f16 scores ------
__global__ __launch_bounds__(512, 4) void k_statsM(
    const f16* __restrict__ xafh, const f16* __restrict__ ench,
    float* __restrict__ Zbuf) {
  int tid = threadIdx.x;
  int w = tid >> 6, lane = tid & 63, quad = lane >> 4, l15 = lane & 15;
  int jb = blockIdx.x * 256 + w * 32;
  int b = jb >> 12;
  f16x8 xa[2][2];
#pragma unroll
  for (int mt = 0; mt < 2; ++mt)
#pragma unroll
    for (int kc = 0; kc < 2; ++kc) {
      size_t off = (size_t)((jb >> 4) + mt) * 1024 + kc * 512 + quad * 128 + l15 * 8;
      xa[mt][kc] = *(const f16x8*)(xafh + off);
    }
  float l_run[8];
#pragma unroll
  for (int s = 0; s < 8; ++s) l_run[s] = 0.f;
  int i0 = blockIdx.y * (TT / SPLIT_A);
  size_t ebase = (size_t)((b * TT + i0) >> 4) * 1024 + quad * 128 + l15 * 8;
  const f16* pEh = ench + ebase;
  for (int it = 0; it < TT / SPLIT_A / 64; ++it) {
    f32x4 acc[2][4];
#pragma unroll
    for (int mt = 0; mt < 2; ++mt)
#pragma unroll
      for (int nt = 0; nt < 4; ++nt) {
        f32x4 z = {0.f, 0.f, 0.f, 0.f};
        acc[mt][nt] = z;
      }
#pragma unroll
    for (int kc = 0; kc < 2; ++kc) {
      f16x8 ebf[4];
#pragma unroll
      for (int nt = 0; nt < 4; ++nt)
        ebf[nt] = *(const f16x8*)(pEh + nt * 1024 + kc * 512);
#pragma unroll
      for (int mt = 0; mt < 2; ++mt)
#pragma unroll
        for (int nt = 0; nt < 4; ++nt)
          acc[mt][nt] = MFMA32(xa[mt][kc], ebf[nt], acc[mt][nt]);
    }
#pragma unroll
    for (int mt = 0; mt < 2; ++mt)
#pragma unroll
      for (int r = 0; r < 4; ++r)
        l_run[mt * 4 + r] += EXP2F(acc[mt][0][r]) + EXP2F(acc[mt][1][r]) +
                             EXP2F(acc[mt][2][r]) + EXP2F(acc[mt][3][r]);
    pEh += 4096;
  }
#pragma unroll
  for (int s = 0; s < 8; ++s) {
    float l = l_run[s];
#pragma unroll
    for (int off = 1; off < 16; off <<= 1) l += __shfl_xor(l, off);
    l_run[s] = l;
  }
  if (l15 == 0) {
#pragma unroll
    for (int mt = 0; mt < 2; ++mt)
#pragma unroll
      for (int r = 0; r < 4; ++r)
        atomicAdd(Zbuf + jb + mt * 16 + quad * 4 + r, l_run[mt * 4 + r]);
  }
}

// ---- pass B: 8 waves share j-stream; depth-1 pipeline; kc-split chains --
__global__ __launch_bounds__(512, 4) void k_outB(
    const f16* __restrict__ xafh, const f16* __restrict__ xafl,
    const f16* __restrict__ xtf,
    const f16* __restrict__ ench, const f16* __restrict__ encl,
    const float* __restrict__ Zv, float* __restrict__ slabs, int jlen) {
  int tid = threadIdx.x;
  int w = tid >> 6, lane = tid & 63, quad = lane >> 4, l15 = lane & 15;
  int ibase = blockIdx.x * 256;
  int iw = ibase + w * 32;
  int b = ibase >> 12;
  f16x8 ebr[2][2][2];
#pragma unroll
  for (int nt = 0; nt < 2; ++nt)
#pragma unroll
    for (int kc = 0; kc < 2; ++kc) {
      size_t off = (size_t)((iw >> 4) + nt) * 1024 + kc * 512 + quad * 128 + l15 * 8;
      ebr[nt][kc][0] = *(const f16x8*)(ench + off);
      ebr[nt][kc][1] = *(const f16x8*)(encl + off);
    }
  f32x4 oacc[2][4];
#pragma unroll
  for (int nt = 0; nt < 2; ++nt)
#pragma unroll
    for (int mtb = 0; mtb < 4; ++mtb) {
      f32x4 z = {0.f, 0.f, 0.f, 0.f};
      oacc[nt][mtb] = z;
    }
  int jt0 = blockIdx.y * jlen;
  int nit = jlen / 16;
  size_t jf0 = (size_t)b * TT + jt0;
  const f16* pAh = xafh + (jf0 >> 4) * 1024 + quad * 128 + l15 * 8;
  const f16* pAl = xafl + (jf0 >> 4) * 1024 + quad * 128 + l15 * 8;
  const f16* pPV = xtf + ((size_t)b * (TT / 16) + (jt0 >> 4)) * 2048 +
                   quad * 512 + l15 * 8;
  const float* pZ = Zv + jf0 + quad * 4;
  // preload tile 0 (all streams)
  f16x8 cah[2], cal[2];
  f16x4 cpv[4];
  float4 cZ;
  cah[0] = *(const f16x8*)(pAh);       cah[1] = *(const f16x8*)(pAh + 512);
  cal[0] = *(const f16x8*)(pAl);       cal[1] = *(const f16x8*)(pAl + 512);
#pragma unroll
  for (int mtb = 0; mtb < 4; ++mtb)
    cpv[mtb] = *(const f16x4*)(pPV + mtb * 128);   // hi half only
  cZ = *(const float4*)pZ;
  pAh += 1024; pAl += 1024; pPV += 2048; pZ += 16;
  for (int t = 0; t < nit; ++t) {
    // prefetch tile t+1 (over-reads stay inside d_ws on last iter)
    f16x8 nah[2], nal[2];
    f16x4 npv[4];
    float4 nZ;
    nah[0] = *(const f16x8*)(pAh);     nah[1] = *(const f16x8*)(pAh + 512);
    nal[0] = *(const f16x8*)(pAl);     nal[1] = *(const f16x8*)(pAl + 512);
#pragma unroll
    for (int mtb = 0; mtb < 4; ++mtb)
      npv[mtb] = *(const f16x4*)(pPV + mtb * 128);
    nZ = *(const float4*)pZ;
    // sT with kc-split accumulators: chain depth 3 instead of 6
    f32x4 s0[2], s1[2];
#pragma unroll
    for (int nt = 0; nt < 2; ++nt) {
      f32x4 z = {0.f, 0.f, 0.f, 0.f};
      s0[nt] = z; s1[nt] = z;
    }
#pragma unroll
    for (int nt = 0; nt < 2; ++nt) {
      s0[nt] = MFMA32(cah[0], ebr[nt][0][0], s0[nt]);
      s1[nt] = MFMA32(cah[1], ebr[nt][1][0], s1[nt]);
      s0[nt] = MFMA32(cah[0], ebr[nt][0][1], s0[nt]);
      s1[nt] = MFMA32(cah[1], ebr[nt][1][1], s1[nt]);
      s0[nt] = MFMA32(cal[0], ebr[nt][0][0], s0[nt]);
      s1[nt] = MFMA32(cal[1], ebr[nt][1][0], s1[nt]);
    }
    // P = exp2(s0+s1) * rZ (PV A-frag layout), hi only
    float rz[4] = {__builtin_amdgcn_rcpf(cZ.x), __builtin_amdgcn_rcpf(cZ.y),
                   __builtin_amdgcn_rcpf(cZ.z), __builtin_amdgcn_rcpf(cZ.w)};
    f16x4 pbh[2];
#pragma unroll
    for (int nt = 0; nt < 2; ++nt)
#pragma unroll
      for (int r = 0; r < 4; ++r)
        pbh[nt][r] = (f16)(EXP2F(s0[nt][r] + s1[nt][r]) * rz[r]);
    // PV: oacc[i,d] += P^T x_hi over this 16-j slice
#pragma unroll
    for (int mtb = 0; mtb < 4; ++mtb)
#pragma unroll
      for (int nt = 0; nt < 2; ++nt)
        oacc[nt][mtb] = MFMA16(pbh[nt], cpv[mtb], oacc[nt][mtb]);
    // rotate
    cah[0] = nah[0]; cah[1] = nah[1];
    cal[0] = nal[0]; cal[1] = nal[1];
#pragma unroll
    for (int mtb = 0; mtb < 4; ++mtb) cpv[mtb] = npv[mtb];
    cZ = nZ;
    pAh += 1024; pAl += 1024; pPV += 2048; pZ += 16;
  }
  // slab stores: D[m=i (quad*4+r), n=d (l15)]
  float* slab = slabs + (size_t)blockIdx.y * BT * 64;
#pragma unroll
  for (int nt = 0; nt < 2; ++nt)
#pragma unroll
    for (int r = 0; r < 4; ++r) {
      int i = iw + nt * 16 + quad * 4 + r;
#pragma unroll
      for (int mtb = 0; mtb < 4; ++mtb)
        slab[(size_t)i * 64 + mtb * 16 + l15] = oacc[nt][mtb][r];
    }
}

// ---- reduce slabs -> out -------------------------------------------------
__global__ __launch_bounds__(256) void k_reduce(const float* __restrict__ slabs,
                                                float* __restrict__ out,
                                                int nsplit) {
  int e = (blockIdx.x * 256 + threadIdx.x) * 4;
  float4 acc = *(const float4*)(slabs + e);
  for (int s = 1; s < nsplit; ++s) {
    float4 v = *(const float4*)(slabs + (size_t)s * BT * 64 + e);
    acc.x += v.x; acc.y += v.y; acc.z += v.z; acc.w += v.w;
  }
  *(float4*)(out + e) = acc;
}

extern "C" void kernel_launch(void* const* d_in, const int* in_sizes, int n_in,
                              void* d_out, int out_size, void* d_ws,
                              size_t ws_size, hipStream_t stream) {
  const float* x = (const float*)d_in[0];
  const float* W1 = (const float*)d_in[1];
  const float* b1 = (const float*)d_in[2];
  const float* W2 = (const float*)d_in[3];
  const float* b2 = (const float*)d_in[4];
  float* out = (float*)d_out;

  f16* xafh = (f16*)d_ws;                       // 2 MB
  f16* xafl = xafh + (size_t)BT * 64;           // 2 MB
  f16* xtf  = xafl + (size_t)BT * 64;           // 4 MB
  f16* ench = xtf + (size_t)BT * 128;           // 2 MB
  f16* encl = ench + (size_t)BT * 64;           // 2 MB
  float* Zv = (float*)(encl + (size_t)BT * 64); // 64 KB
  f16* w1fh = (f16*)(Zv + BT + 1024);           // +pad for Z over-read
  f16* w1fl = w1fh + 4096;                      // 8 KB each
  f16* w2fh = w1fl + 4096;
  f16* w2fl = w2fh + 4096;
  float* slabs = (float*)(w2fl + 4096);         // NSPLIT_B * 4 MB

  k_wpack<<<dim3(1), dim3(256), 0, stream>>>(W1, W2, w1fh, w1fl, w2fh, w2fl);
  k_encode<<<dim3(BT / 64), dim3(256), 0, stream>>>(
      x, b1, b2, w1fh, w1fl, w2fh, w2fl, ench, encl, xafh, xafl, xtf, Zv);
  k_statsM<<<dim3(BT / 256, SPLIT_A), dim3(512), 0, stream>>>(xafh, ench, Zv);
  k_outB<<<dim3(BT / 256, NSPLIT_B), dim3(512), 0, stream>>>(
      xafh, xafl, xtf, ench, encl, Zv, slabs, TT / NSPLIT_B);
  k_reduce<<<dim3(BT * 64 / 1024), dim3(256), 0, stream>>>(slabs, out, NSPLIT_B);
}